// Round 6
// baseline (197.037 us; speedup 1.0000x reference)
//
#include <hip/hip_runtime.h>

// Problem constants (from reference setup_inputs)
constexpr int B  = 32;
constexpr int C  = 3;
constexpr int H  = 512;
constexpr int W  = 512;
constexpr int HP = H / 4;    // 128 pooled rows
constexpr int WP = W / 4;    // 128 pooled cols
constexpr int NP = B * HP * WP;   // 524288 pooled pixels
constexpr int W4 = W / 4;    // 128 float4 per image row

// v7: occupancy retest in the HBM-stream regime.
// v6 (nt loads) broke the 2.8 TB/s wall of v1-v5: kernel ~77.5 -> ~54us
// (~4 TB/s). H2 confirmed: the Infinity-Cache-HIT service path (~1.4
// TB/s) was rate-limiting; nt bypasses allocation so the whole stream
// rides the HBM read path (harness fill kernel proves ~6.9 TB/s
// one-directional). New regime -> latency/TLP matters again: a pure-HBM
// stream needs ~9KB in flight/CU; v6 ran 1 block/CU (16 waves).
// v7: ROWS_PB 16->8 -> 512 blocks = 2 blocks/CU = 32 waves/CU
// (launch_bounds(1024,2)). Halo cost 6.25->12.5% (214->225MB, +2.8us at
// 4 TB/s) which doubled TLP must beat. Null -> revert geometry, declare.
typedef float f4 __attribute__((ext_vector_type(4)));

constexpr int ROWS_PB     = 8;               // owned pooled rows per block
constexpr int HROWS       = ROWS_PB + 1;     // 9 incl. top halo
constexpr int BLK_PER_IMG = HP / ROWS_PB;    // 16
constexpr int NBLOCKS     = B * BLK_PER_IMG; // 512 -> 2 blocks/CU
constexpr int NTHR        = 1024;
constexpr int NTASK       = C * HROWS * WP;  // 3456 load-tasks per block

__global__ __launch_bounds__(1024, 2) void spatial_loss_fused(
        const float* __restrict__ x,
        const float* __restrict__ pred,
        float* __restrict__ out) {
    __shared__ float sm[C * HROWS][WP];   // 27 x 128 = 13.8 KB per-(c,row) partials
    __shared__ float P[HROWS][WP];        // 9 x 128 pooled diff tile
    __shared__ float ws_red[16];

    // Bijective XCD swizzle (512 % 8 == 0): vertically-adjacent blocks
    // (which share a halo row) land on the same XCD's L2.
    int orig = blockIdx.x;
    int blk  = (orig & 7) * (NBLOCKS / 8) + (orig >> 3);
    int b    = blk >> 4;          // image
    int br   = blk & 15;          // block-row within image
    int py0  = br * ROWS_PB;
    int tid  = threadIdx.x;

    const f4* __restrict__ xb = (const f4*)x;
    const f4* __restrict__ pb = (const f4*)pred;

    // ---- Phase A: per-(channel, pooled-pixel) partial diffs ----
    // task t -> q = t&127 (float4 col), cr = t>>7 in 0..26 ->
    //   rr = cr/3 (local pooled row incl. top halo), c = cr%3.
    // Wave lanes have consecutive q -> every load is 1KB contiguous.
    // 3456 tasks / 1024 thr = 4 iters (last = 384 thr, wave-uniform).
    for (int t = tid; t < NTASK; t += NTHR) {
        int q  = t & 127;
        int cr = t >> 7;
        int rr = cr / 3;              // 0..8 (0 = top halo row)
        int c  = cr - 3 * rr;
        int gy = py0 + rr - 1;        // pooled row, -1..127
        float s = 0.0f;
        if (gy >= 0) {                // wave-uniform guard (br==0 only)
            int a = ((b * C + c) * H + gy * 4) * W4 + q;
            // 8 independent non-temporal loads batched before arithmetic.
            f4 x0 = __builtin_nontemporal_load(xb + a);
            f4 x1 = __builtin_nontemporal_load(xb + a + W4);
            f4 x2 = __builtin_nontemporal_load(xb + a + 2 * W4);
            f4 x3 = __builtin_nontemporal_load(xb + a + 3 * W4);
            f4 p0 = __builtin_nontemporal_load(pb + a);
            f4 p1 = __builtin_nontemporal_load(pb + a + W4);
            f4 p2 = __builtin_nontemporal_load(pb + a + 2 * W4);
            f4 p3 = __builtin_nontemporal_load(pb + a + 3 * W4);
            float s0 = (x0.x - p0.x) + (x0.y - p0.y) + (x0.z - p0.z) + (x0.w - p0.w);
            float s1 = (x1.x - p1.x) + (x1.y - p1.y) + (x1.z - p1.z) + (x1.w - p1.w);
            float s2 = (x2.x - p2.x) + (x2.y - p2.y) + (x2.z - p2.z) + (x2.w - p2.w);
            float s3 = (x3.x - p3.x) + (x3.y - p3.y) + (x3.z - p3.z) + (x3.w - p3.w);
            s = (s0 + s1) + (s2 + s3);
        }
        sm[cr][q] = s;   // lanes -> consecutive q, conflict-free
    }
    __syncthreads();

    // ---- Phase B1: channel-sum -> pooled diff tile P (9 x 128) ----
    // For br==0 the halo tasks wrote s=0 -> P[0]=0 at the image top.
    for (int i = tid; i < HROWS * WP; i += NTHR) {
        int q  = i & 127;
        int pr = i >> 7;              // 0..8
        P[pr][q] = (sm[3 * pr][q] + sm[3 * pr + 1][q] + sm[3 * pr + 2][q])
                   * (1.0f / 48.0f);
    }
    __syncthreads();

    // ---- Phase B2: pair-counted gradient sum over owned 8x128 pixels ----
    // E*NP = 2*sum(adjacent-pair diffs^2) + sum(border p^2); this block
    // counts the up-pair and left-pair of its OWNED pixels. Zero halo at
    // the image top makes the border term c^2 with weight 1 automatically.
    float acc;
    {
        int q  = tid & 127;
        int r  = tid >> 7;            // 0..7
        int gy = py0 + r;
        float cv = P[r + 1][q];
        float up = P[r][q];                       // 0 if gy==0
        float lf = (q > 0) ? P[r + 1][q - 1] : 0.0f;
        float dy = cv - up;
        float dx = cv - lf;
        float wy = (gy > 0) ? 2.0f : 1.0f;        // interior pair counted twice
        float wx = (q  > 0) ? 2.0f : 1.0f;
        acc = wy * dy * dy + wx * dx * dx;
        if (gy == HP - 1) acc += cv * cv;         // bottom border (d_down)
        if (q  == WP - 1) acc += cv * cv;         // right border (d_right)
    }

    // wave64 shuffle reduce -> LDS -> one pre-scaled atomicAdd per block
    #pragma unroll
    for (int off = 32; off > 0; off >>= 1)
        acc += __shfl_down(acc, off, 64);

    int lane = tid & 63;
    int wid  = tid >> 6;              // 0..15
    if (lane == 0) ws_red[wid] = acc;
    __syncthreads();
    if (tid == 0) {
        float s = 0.0f;
        #pragma unroll
        for (int k = 0; k < 16; ++k) s += ws_red[k];
        atomicAdd(out, s * (1.0f / (float)NP));
    }
}

extern "C" void kernel_launch(void* const* d_in, const int* in_sizes, int n_in,
                              void* d_out, int out_size, void* d_ws, size_t ws_size,
                              hipStream_t stream) {
    const float* x    = (const float*)d_in[0];
    const float* pred = (const float*)d_in[1];
    float* out = (float*)d_out;

    // d_out is poisoned 0xAA before every launch — zero it (capture-safe).
    hipMemsetAsync(out, 0, sizeof(float), stream);

    spatial_loss_fused<<<NBLOCKS, NTHR, 0, stream>>>(x, pred, out);
}